// Round 1
// baseline (136.569 us; speedup 1.0000x reference)
//
#include <hip/hip_runtime.h>
#include <stdint.h>

#define BB 256
#define CC 64
#define CVV 4
#define LL 2048

// ---------------------------------------------------------------------------
// Kernel 0: detect how the bool mask was marshaled.
// Scans the first B*L/4 u32 words (512 KB — safe under byte, int32, or f32
// layout since the smallest possible buffer is 512 KB).
//   byte layout  : words pack 4 random 0/1 bytes -> some word >1 and != 1.0f
//   float layout : words in {0x00000000, 0x3F800000}
//   int32 layout : words in {0, 1}
// flags bit0 = byte layout, bit1 = float layout, neither = int32 layout.
// ---------------------------------------------------------------------------
__global__ __launch_bounds__(256) void detect_kernel(const unsigned* maskw,
                                                     unsigned* flags) {
  unsigned f = 0;
  const int NW = (BB * LL) / 4;
  for (int w = blockIdx.x * blockDim.x + threadIdx.x; w < NW;
       w += gridDim.x * blockDim.x) {
    unsigned val = maskw[w];
    if (val == 0x3F800000u) f |= 2u;
    else if (val > 1u)      f |= 1u;
  }
  if (f) atomicOr(flags, f);
}

// ---------------------------------------------------------------------------
// Kernel 1: per-batch stable descending argsort of rand_f via bitonic sort of
// 64-bit composite keys in LDS. Key = ord(rand_f)<<32 | (L-1-idx), so a plain
// descending sort gives: primary rand_f descending, ties by ascending index —
// exactly jnp's stable argsort(-rand_f).
// Emits staged int per output position j into the mask region of d_out:
//   bits[10:0] = source index, bit11 = masked, bit12 = keep (j < maxlen).
// ---------------------------------------------------------------------------
__global__ __launch_bounds__(256) void sortperm_kernel(const void* mask,
                                                       const float* rnd,
                                                       const unsigned* flags,
                                                       int* stage) {
  __shared__ unsigned long long key[LL];
  __shared__ int cnt;
  const int b = blockIdx.x;
  const int tid = threadIdx.x;
  if (tid == 0) cnt = 0;
  __syncthreads();

  const unsigned fl = *flags;
  const int layout = (fl & 1u) ? 1 : ((fl & 2u) ? 2 : 0);

  int local = 0;
  for (int l = tid; l < LL; l += 256) {
    bool m;
    if (layout == 1)      m = ((const unsigned char*)mask)[b * LL + l] != 0;
    else if (layout == 2) m = ((const float*)mask)[b * LL + l] != 0.0f;
    else                  m = ((const int*)mask)[b * LL + l] != 0;
    float rf = m ? -1.0f : rnd[b * LL + l];
    unsigned u = __float_as_uint(rf);
    u = (u & 0x80000000u) ? ~u : (u | 0x80000000u);  // order-preserving map
    key[l] = ((unsigned long long)u << 32) | (unsigned)(LL - 1 - l);
    local += m ? 1 : 0;
  }
  if (local) atomicAdd(&cnt, local);
  __syncthreads();

  // Bitonic sort, descending. 2048 elems, 256 threads -> 4 CE pairs/thread.
  for (int size = 2; size <= LL; size <<= 1) {
    for (int stride = size >> 1; stride > 0; stride >>= 1) {
      for (int t = tid; t < LL / 2; t += 256) {
        int i = ((t & ~(stride - 1)) << 1) | (t & (stride - 1));
        int j = i + stride;
        unsigned long long a = key[i];
        unsigned long long c = key[j];
        bool descBlk = ((i & size) == 0);
        bool sw = descBlk ? (a < c) : (a > c);
        if (sw) { key[i] = c; key[j] = a; }
      }
      __syncthreads();
    }
  }

  const int maxlen = cnt > 1 ? cnt : 1;          // jnp.maximum(count, 1)
  const unsigned ordNeg1 = ~__float_as_uint(-1.0f);  // ord(-1.0) = 0x407FFFFF
  for (int j = tid; j < LL; j += 256) {
    unsigned long long k2 = key[j];
    int idx = (LL - 1) - (int)(unsigned)(k2 & 0xFFFFFFFFull);
    bool masked = ((unsigned)(k2 >> 32)) == ordNeg1;
    stage[b * LL + j] =
        idx | (masked ? (1 << 11) : 0) | ((j < maxlen) ? (1 << 12) : 0);
  }
}

// ---------------------------------------------------------------------------
// Kernel 2: gather x and v rows through the staged permutation; coalesced
// writes, gathered reads (each 8 KB source row stays L1-resident).
// ---------------------------------------------------------------------------
__global__ __launch_bounds__(256) void gather_kernel(const float* __restrict__ x,
                                                     const float* __restrict__ v,
                                                     const int* __restrict__ stage,
                                                     float* __restrict__ xo,
                                                     float* __restrict__ vo) {
  const int blk = blockIdx.x;
  const int b = blk / (CC + CVV);
  const int r = blk % (CC + CVV);
  const float* in;
  float* out;
  if (r < CC) {
    in  = x  + ((size_t)b * CC + r) * LL;
    out = xo + ((size_t)b * CC + r) * LL;
  } else {
    in  = v  + ((size_t)b * CVV + (r - CC)) * LL;
    out = vo + ((size_t)b * CVV + (r - CC)) * LL;
  }
  const int* st = stage + b * LL;
  for (int j = threadIdx.x; j < LL; j += 256) {
    int s = st[j];
    out[j] = (s & (1 << 12)) ? in[s & 0x7FF] : 0.0f;
  }
}

// ---------------------------------------------------------------------------
// Kernel 3: convert staged ints in place to the final mask floats (0.0/1.0).
// Runs after gather_kernel (stream-ordered), so reads are done.
// ---------------------------------------------------------------------------
__global__ __launch_bounds__(256) void maskout_kernel(int* stage,
                                                      float* mout) {
  const int i = blockIdx.x * 256 + threadIdx.x;  // grid covers B*L exactly
  int s = stage[i];
  float val = ((s & (1 << 12)) && (s & (1 << 11))) ? 1.0f : 0.0f;
  mout[i] = val;
}

extern "C" void kernel_launch(void* const* d_in, const int* in_sizes, int n_in,
                              void* d_out, int out_size, void* d_ws, size_t ws_size,
                              hipStream_t stream) {
  const float* x    = (const float*)d_in[0];
  const float* v    = (const float*)d_in[1];
  const void*  mask = d_in[2];
  const float* rnd  = (const float*)d_in[3];

  float* xo = (float*)d_out;                                    // B*C*L
  float* vo = xo + (size_t)BB * CC * LL;                        // B*CV*L
  float* mo = vo + (size_t)BB * CVV * LL;                       // B*1*L
  int* stage = (int*)mo;

  unsigned* flags = (unsigned*)d_ws;
  hipMemsetAsync(d_ws, 0, 16, stream);

  detect_kernel<<<64, 256, 0, stream>>>((const unsigned*)mask, flags);
  sortperm_kernel<<<BB, 256, 0, stream>>>(mask, rnd, flags, stage);
  gather_kernel<<<BB * (CC + CVV), 256, 0, stream>>>(x, v, stage, xo, vo);
  maskout_kernel<<<(BB * LL) / 256, 256, 0, stream>>>(stage, mo);
}

// Round 2
// 83.250 us; speedup vs baseline: 1.6405x; 1.6405x over previous
//
#include <hip/hip_runtime.h>
#include <stdint.h>

#define BB 256
#define CC 64
#define CVV 4
#define LL 2048
#define CHUNKS 17  // 68 rows / 4 rows per block

// ---------------------------------------------------------------------------
// Kernel 1: per-batch stable descending argsort of rand_f via bitonic sort of
// 64-bit composite keys in LDS. Key = ord(rand_f)<<32 | (L-1-idx), so a plain
// descending sort gives: primary rand_f descending, ties by ascending index —
// exactly jnp's stable argsort(-rand_f).
//
// Mask layout (bool marshaling) is self-detected per block from a disjoint
// 512-word slice of the mask buffer (every slice contains random 0/1 data in
// all three candidate layouts; misdetection probability ~2^-512):
//   byte layout  : some packed word > 1 (and != 0x3F800000)
//   float layout : sees 0x3F800000
//   int32 layout : only {0,1} words
//
// Emits staged int per output position j into the mask region of d_out:
//   bits[10:0] = source index, bit11 = masked, bit12 = keep (j < maxlen).
// ---------------------------------------------------------------------------
__global__ __launch_bounds__(512) void sortperm_kernel(const void* mask,
                                                       const float* rnd,
                                                       int* stage) {
  __shared__ unsigned long long key[LL];
  __shared__ int cnt;
  __shared__ unsigned detf;
  const int b = blockIdx.x;
  const int tid = threadIdx.x;
  if (tid == 0) { cnt = 0; detf = 0; }
  __syncthreads();

  // --- self-detect mask layout from words [b*512, b*512+512) ---
  {
    unsigned val = ((const unsigned*)mask)[b * 512 + tid];
    unsigned f = 0;
    if (val == 0x3F800000u) f = 2u;
    else if (val > 1u)      f = 1u;
    if (f) atomicOr(&detf, f);
  }
  __syncthreads();
  const unsigned fl = detf;
  const int layout = (fl & 1u) ? 1 : ((fl & 2u) ? 2 : 0);

  int local = 0;
  for (int l = tid; l < LL; l += 512) {
    bool m;
    if (layout == 1)      m = ((const unsigned char*)mask)[b * LL + l] != 0;
    else if (layout == 2) m = ((const float*)mask)[b * LL + l] != 0.0f;
    else                  m = ((const int*)mask)[b * LL + l] != 0;
    float rf = m ? -1.0f : rnd[b * LL + l];
    unsigned u = __float_as_uint(rf);
    u = (u & 0x80000000u) ? ~u : (u | 0x80000000u);  // order-preserving map
    key[l] = ((unsigned long long)u << 32) | (unsigned)(LL - 1 - l);
    local += m ? 1 : 0;
  }
  if (local) atomicAdd(&cnt, local);
  __syncthreads();

  // Bitonic sort, descending. 2048 elems, 512 threads -> 2 CE pairs/thread.
  for (int size = 2; size <= LL; size <<= 1) {
    for (int stride = size >> 1; stride > 0; stride >>= 1) {
      for (int t = tid; t < LL / 2; t += 512) {
        int i = ((t & ~(stride - 1)) << 1) | (t & (stride - 1));
        int j = i + stride;
        unsigned long long a = key[i];
        unsigned long long c = key[j];
        bool descBlk = ((i & size) == 0);
        bool sw = descBlk ? (a < c) : (a > c);
        if (sw) { key[i] = c; key[j] = a; }
      }
      __syncthreads();
    }
  }

  const int maxlen = cnt > 1 ? cnt : 1;              // jnp.maximum(count, 1)
  const unsigned ordNeg1 = ~__float_as_uint(-1.0f);  // ord(-1.0)
  for (int j = tid; j < LL; j += 512) {
    unsigned long long k2 = key[j];
    int idx = (LL - 1) - (int)(unsigned)(k2 & 0xFFFFFFFFull);
    bool masked = ((unsigned)(k2 >> 32)) == ordNeg1;
    stage[b * LL + j] =
        idx | (masked ? (1 << 11) : 0) | ((j < maxlen) ? (1 << 12) : 0);
  }
}

// ---------------------------------------------------------------------------
// Kernel 2: gather x and v rows through the staged permutation.
// Block = (batch, chunk of 4 rows). Perm entries live in registers (8/thread);
// the 8 KB source row is staged in LDS via coalesced float4 loads; gather is
// an LDS read (random banks ~ 2-way conflict, nearly free); writes are
// coalesced float4. All global traffic is fully vectorized.
// ---------------------------------------------------------------------------
__global__ __launch_bounds__(256) void gather_kernel(const float* __restrict__ x,
                                                     const float* __restrict__ v,
                                                     const int* __restrict__ stage,
                                                     float* __restrict__ xo,
                                                     float* __restrict__ vo) {
  __shared__ float row[LL];
  const int b = blockIdx.x / CHUNKS;
  const int chunk = blockIdx.x % CHUNKS;
  const int tid = threadIdx.x;

  // Perm entries for this thread's two output float4s (coalesced int4 loads).
  const int4* st4 = (const int4*)(stage + b * LL);
  const int4 s_lo = st4[tid];
  const int4 s_hi = st4[tid + 256];

  for (int rr = 0; rr < 4; ++rr) {
    const int r = chunk * 4 + rr;  // 0..67: 0-63 -> x rows, 64-67 -> v rows
    const float4* in4;
    float4* out4;
    if (r < CC) {
      in4  = (const float4*)(x  + ((size_t)b * CC + r) * LL);
      out4 = (float4*)(xo + ((size_t)b * CC + r) * LL);
    } else {
      in4  = (const float4*)(v  + ((size_t)b * CVV + (r - CC)) * LL);
      out4 = (float4*)(vo + ((size_t)b * CVV + (r - CC)) * LL);
    }
    __syncthreads();  // previous iteration's gathers done before overwrite
    ((float4*)row)[tid]       = in4[tid];
    ((float4*)row)[tid + 256] = in4[tid + 256];
    __syncthreads();

    float4 o;
    o.x = (s_lo.x & (1 << 12)) ? row[s_lo.x & 0x7FF] : 0.0f;
    o.y = (s_lo.y & (1 << 12)) ? row[s_lo.y & 0x7FF] : 0.0f;
    o.z = (s_lo.z & (1 << 12)) ? row[s_lo.z & 0x7FF] : 0.0f;
    o.w = (s_lo.w & (1 << 12)) ? row[s_lo.w & 0x7FF] : 0.0f;
    out4[tid] = o;
    o.x = (s_hi.x & (1 << 12)) ? row[s_hi.x & 0x7FF] : 0.0f;
    o.y = (s_hi.y & (1 << 12)) ? row[s_hi.y & 0x7FF] : 0.0f;
    o.z = (s_hi.z & (1 << 12)) ? row[s_hi.z & 0x7FF] : 0.0f;
    o.w = (s_hi.w & (1 << 12)) ? row[s_hi.w & 0x7FF] : 0.0f;
    out4[tid + 256] = o;
  }
}

// ---------------------------------------------------------------------------
// Kernel 3: convert staged ints in place to the final mask floats (0.0/1.0).
// Runs after gather_kernel (stream-ordered), so all stage reads are done.
// ---------------------------------------------------------------------------
__global__ __launch_bounds__(256) void maskout_kernel(int* stage,
                                                      float* mout) {
  const int i = blockIdx.x * 256 + threadIdx.x;  // grid covers B*L exactly
  int s = stage[i];
  float val = ((s & (1 << 12)) && (s & (1 << 11))) ? 1.0f : 0.0f;
  mout[i] = val;
}

extern "C" void kernel_launch(void* const* d_in, const int* in_sizes, int n_in,
                              void* d_out, int out_size, void* d_ws, size_t ws_size,
                              hipStream_t stream) {
  const float* x    = (const float*)d_in[0];
  const float* v    = (const float*)d_in[1];
  const void*  mask = d_in[2];
  const float* rnd  = (const float*)d_in[3];

  float* xo = (float*)d_out;                  // B*C*L
  float* vo = xo + (size_t)BB * CC * LL;      // B*CV*L
  float* mo = vo + (size_t)BB * CVV * LL;     // B*1*L
  int* stage = (int*)mo;

  sortperm_kernel<<<BB, 512, 0, stream>>>(mask, rnd, stage);
  gather_kernel<<<BB * CHUNKS, 256, 0, stream>>>(x, v, stage, xo, vo);
  maskout_kernel<<<(BB * LL) / 256, 256, 0, stream>>>(stage, mo);
}

// Round 3
// 73.281 us; speedup vs baseline: 1.8636x; 1.1360x over previous
//
#include <hip/hip_runtime.h>
#include <stdint.h>

#define BB 256
#define CC 64
#define CVV 4
#define LL 2048
#define CHUNKS 17  // 68 rows / 4 rows per block

__device__ __forceinline__ void ce_desc(unsigned long long* key, int i, int j,
                                        bool descBlk) {
  unsigned long long a = key[i], c = key[j];
  bool sw = descBlk ? (a < c) : (a > c);
  if (sw) { key[i] = c; key[j] = a; }
}

// ---------------------------------------------------------------------------
// Kernel 1: per-batch stable descending argsort of rand_f via bitonic sort of
// 64-bit composite keys (ord(rand_f)<<32 | (L-1-idx)) in LDS.
// Wave-segment optimization: wave w owns elements [w*256,(w+1)*256). Every
// substage with stride <= 128 pairs elements within one segment (2*stride <=
// 256), so it needs only same-wave DS ordering (in-order DS pipe + compiler
// lgkmcnt) — no block barrier. Block barriers remain only around stride>=256
// substages: ~10 total instead of 66.
// Mask layout self-detected per block from a disjoint 512-word slice.
// Writes stage ints (idx | masked<<11 | keep<<12) and, if mout != nullptr,
// the final mask_t floats directly.
// ---------------------------------------------------------------------------
__global__ __launch_bounds__(512) void sortperm_kernel(const void* mask,
                                                       const float* rnd,
                                                       int* stage,
                                                       float* mout) {
  __shared__ unsigned long long key[LL];
  __shared__ int cnt;
  __shared__ unsigned detf;
  const int b = blockIdx.x;
  const int tid = threadIdx.x;
  if (tid == 0) { cnt = 0; detf = 0; }
  __syncthreads();

  // --- self-detect mask layout from words [b*512, b*512+512) ---
  {
    unsigned val = ((const unsigned*)mask)[b * 512 + tid];
    unsigned f = (val == 0x3F800000u) ? 2u : (val > 1u ? 1u : 0u);
    if (f) atomicOr(&detf, f);
  }
  __syncthreads();
  const unsigned fl = detf;
  const int layout = (fl & 1u) ? 1 : ((fl & 2u) ? 2 : 0);

  int local = 0;
  for (int l = tid; l < LL; l += 512) {
    bool m;
    if (layout == 1)      m = ((const unsigned char*)mask)[b * LL + l] != 0;
    else if (layout == 2) m = ((const float*)mask)[b * LL + l] != 0.0f;
    else                  m = ((const int*)mask)[b * LL + l] != 0;
    float rf = m ? -1.0f : rnd[b * LL + l];
    unsigned u = __float_as_uint(rf);
    u = (u & 0x80000000u) ? ~u : (u | 0x80000000u);  // order-preserving map
    key[l] = ((unsigned long long)u << 32) | (unsigned)(LL - 1 - l);
    local += m ? 1 : 0;
  }
  if (local) atomicAdd(&cnt, local);
  __syncthreads();

  const int w = tid >> 6;    // wave id 0..7 owns key[w*256 .. w*256+255]
  const int lane = tid & 63;

  // sizes 2..256: every stride <= 128 -> fully wave-local, no block barrier
  for (int size = 2; size <= 256; size <<= 1) {
    for (int stride = size >> 1; stride > 0; stride >>= 1) {
#pragma unroll
      for (int pp = 0; pp < 2; ++pp) {
        int p = w * 128 + pp * 64 + lane;  // pair indices of segment w
        int i = ((p & ~(stride - 1)) << 1) | (p & (stride - 1));
        ce_desc(key, i, i + stride, (i & size) == 0);
      }
      __builtin_amdgcn_wave_barrier();
    }
  }
  __syncthreads();

  // sizes 512..2048: strides >= 256 cross segments (barriered), rest local
  for (int size = 512; size <= 2048; size <<= 1) {
    for (int stride = size >> 1; stride >= 256; stride >>= 1) {
      for (int t = tid; t < LL / 2; t += 512) {
        int i = ((t & ~(stride - 1)) << 1) | (t & (stride - 1));
        ce_desc(key, i, i + stride, (i & size) == 0);
      }
      __syncthreads();
    }
    for (int stride = 128; stride > 0; stride >>= 1) {
#pragma unroll
      for (int pp = 0; pp < 2; ++pp) {
        int p = w * 128 + pp * 64 + lane;
        int i = ((p & ~(stride - 1)) << 1) | (p & (stride - 1));
        ce_desc(key, i, i + stride, (i & size) == 0);
      }
      __builtin_amdgcn_wave_barrier();
    }
    __syncthreads();
  }

  const int maxlen = cnt > 1 ? cnt : 1;              // jnp.maximum(count, 1)
  const unsigned ordNeg1 = ~__float_as_uint(-1.0f);  // ord(-1.0)
  for (int j = tid; j < LL; j += 512) {
    unsigned long long k2 = key[j];
    int idx = (LL - 1) - (int)(unsigned)(k2 & 0xFFFFFFFFull);
    bool masked = ((unsigned)(k2 >> 32)) == ordNeg1;
    bool keep = j < maxlen;
    stage[b * LL + j] =
        idx | (masked ? (1 << 11) : 0) | (keep ? (1 << 12) : 0);
    if (mout) mout[b * LL + j] = (keep && masked) ? 1.0f : 0.0f;
  }
}

// ---------------------------------------------------------------------------
// Kernel 2: gather x and v rows through the staged permutation.
// Block = (batch, chunk of 4 rows); perm entries in registers (8/thread);
// software-pipelined: row rr+1 is loaded to registers while row rr is
// gathered from LDS, so global-load latency hides under the gather+store
// phase. All global traffic is coalesced float4.
// ---------------------------------------------------------------------------
__global__ __launch_bounds__(256) void gather_kernel(const float* __restrict__ x,
                                                     const float* __restrict__ v,
                                                     const int* __restrict__ stage,
                                                     float* __restrict__ xo,
                                                     float* __restrict__ vo) {
  __shared__ float row[LL];
  const int b = blockIdx.x / CHUNKS;
  const int chunk = blockIdx.x % CHUNKS;
  const int tid = threadIdx.x;

  const int4* st4 = (const int4*)(stage + b * LL);
  const int4 s_lo = st4[tid];
  const int4 s_hi = st4[tid + 256];

  const float4* in4[4];
  float4* out4[4];
#pragma unroll
  for (int rr = 0; rr < 4; ++rr) {
    const int r = chunk * 4 + rr;  // 0..67: 0-63 -> x rows, 64-67 -> v rows
    if (r < CC) {
      in4[rr]  = (const float4*)(x  + ((size_t)b * CC + r) * LL);
      out4[rr] = (float4*)(xo + ((size_t)b * CC + r) * LL);
    } else {
      in4[rr]  = (const float4*)(v  + ((size_t)b * CVV + (r - CC)) * LL);
      out4[rr] = (float4*)(vo + ((size_t)b * CVV + (r - CC)) * LL);
    }
  }

  float4 p0 = in4[0][tid];
  float4 p1 = in4[0][tid + 256];
#pragma unroll
  for (int rr = 0; rr < 4; ++rr) {
    __syncthreads();  // previous iteration's gathers done before overwrite
    ((float4*)row)[tid]       = p0;
    ((float4*)row)[tid + 256] = p1;
    __syncthreads();
    if (rr + 1 < 4) {  // prefetch next row; latency overlaps gather below
      p0 = in4[rr + 1][tid];
      p1 = in4[rr + 1][tid + 256];
    }
    float4 o;
    o.x = (s_lo.x & (1 << 12)) ? row[s_lo.x & 0x7FF] : 0.0f;
    o.y = (s_lo.y & (1 << 12)) ? row[s_lo.y & 0x7FF] : 0.0f;
    o.z = (s_lo.z & (1 << 12)) ? row[s_lo.z & 0x7FF] : 0.0f;
    o.w = (s_lo.w & (1 << 12)) ? row[s_lo.w & 0x7FF] : 0.0f;
    out4[rr][tid] = o;
    o.x = (s_hi.x & (1 << 12)) ? row[s_hi.x & 0x7FF] : 0.0f;
    o.y = (s_hi.y & (1 << 12)) ? row[s_hi.y & 0x7FF] : 0.0f;
    o.z = (s_hi.z & (1 << 12)) ? row[s_hi.z & 0x7FF] : 0.0f;
    o.w = (s_hi.w & (1 << 12)) ? row[s_hi.w & 0x7FF] : 0.0f;
    out4[rr][tid + 256] = o;
  }
}

// ---------------------------------------------------------------------------
// Kernel 3 (fallback only, when ws is too small and stage aliases the mask
// output): convert staged ints in place to the final mask floats.
// ---------------------------------------------------------------------------
__global__ __launch_bounds__(256) void maskout_kernel(int* stage,
                                                      float* mout) {
  const int i = blockIdx.x * 256 + threadIdx.x;  // grid covers B*L exactly
  int s = stage[i];
  mout[i] = ((s & (1 << 12)) && (s & (1 << 11))) ? 1.0f : 0.0f;
}

extern "C" void kernel_launch(void* const* d_in, const int* in_sizes, int n_in,
                              void* d_out, int out_size, void* d_ws, size_t ws_size,
                              hipStream_t stream) {
  const float* x    = (const float*)d_in[0];
  const float* v    = (const float*)d_in[1];
  const void*  mask = d_in[2];
  const float* rnd  = (const float*)d_in[3];

  float* xo = (float*)d_out;                  // B*C*L
  float* vo = xo + (size_t)BB * CC * LL;      // B*CV*L
  float* mo = vo + (size_t)BB * CVV * LL;     // B*1*L

  const bool use_ws = ws_size >= (size_t)BB * LL * sizeof(int);
  int* stage = use_ws ? (int*)d_ws : (int*)mo;

  sortperm_kernel<<<BB, 512, 0, stream>>>(mask, rnd, stage,
                                          use_ws ? mo : nullptr);
  gather_kernel<<<BB * CHUNKS, 256, 0, stream>>>(x, v, stage, xo, vo);
  if (!use_ws)
    maskout_kernel<<<(BB * LL) / 256, 256, 0, stream>>>(stage, mo);
}